// Round 22
// baseline (72.970 us; speedup 1.0000x reference)
//
#include <hip/hip_runtime.h>

#define TSEQ 4096
#define DM 512
#define NH 8
#define HS 64
#define CTX 256

typedef __attribute__((ext_vector_type(8))) short bf16x8;
typedef __attribute__((ext_vector_type(4))) float f32x4;
typedef unsigned short u16;
typedef unsigned long long ull;

__device__ __forceinline__ u16 f2bf(float x) {
    unsigned u = __float_as_uint(x);
    unsigned r = (u + 0x7fffu + ((u >> 16) & 1u)) >> 16;
    return (u16)r;
}
__device__ __forceinline__ float bf2f(u16 b) {
    return __uint_as_float(((unsigned)b) << 16);
}
__device__ __forceinline__ unsigned bf16dup(float p) {
    unsigned w;
    asm("v_cvt_pk_bf16_f32 %0, %1, %1" : "=v"(w) : "v"(p));
    return w;
}
template<int CTRL>
__device__ __forceinline__ float dpp_ror(float x) {
    int xi = __float_as_int(x);
    return __int_as_float(__builtin_amdgcn_update_dpp(xi, xi, CTRL, 0xf, 0xf, false));
}
__device__ __forceinline__ float row16_max(float v) {
    v = fmaxf(v, dpp_ror<0x121>(v));
    v = fmaxf(v, dpp_ror<0x122>(v));
    v = fmaxf(v, dpp_ror<0x124>(v));
    v = fmaxf(v, dpp_ror<0x128>(v));
    return v;
}

#define MFMA(a, b, c) __builtin_amdgcn_mfma_f32_16x16x32_bf16((a), (b), (c), 0, 0, 0)

// ---------------------------------------------------------------------------
// Fused pre-split: X (blocks 0..2047) + transposed weights (2048..5119).
// ---------------------------------------------------------------------------
__global__ __launch_bounds__(256) void presplit_xw(
    const float* __restrict__ X,
    const float* __restrict__ WQ, const float* __restrict__ WV,
    const float* __restrict__ WU,
    u16* __restrict__ Xh,
    u16* __restrict__ WQt_h, u16* __restrict__ WVt_h, u16* __restrict__ WUt_h)
{
    int b = blockIdx.x;
    if (b < 2048) {
        size_t idx = ((size_t)b * 256 + threadIdx.x) * 8;
        float4 p0 = *(const float4*)(X + idx);
        float4 p1 = *(const float4*)(X + idx + 4);
        float v[8] = {p0.x, p0.y, p0.z, p0.w, p1.x, p1.y, p1.z, p1.w};
        bf16x8 h;
        #pragma unroll
        for (int i = 0; i < 8; ++i) h[i] = (short)f2bf(v[i]);
        *(bf16x8*)(Xh + idx) = h;
    } else {
        int gidx = (b - 2048) * 256 + threadIdx.x;   // 0 .. 786431
        int a = gidx >> 18;                          // 0: WQ, 1: WV, 2: WU
        int r = gidx & 262143;
        float val;
        u16* dh;
        int dst;
        if (a < 2) {
            int h = r >> 15, s = (r >> 9) & 63, d = r & 511;
            const float* W = (a == 0) ? WQ : WV;
            val = W[h * 32768 + d * 64 + s];
            dst = h * 32768 + s * 512 + d;
            dh = (a == 0) ? WQt_h : WVt_h;
        } else {
            int n = r >> 9, k = r & 511;
            val = WU[k * 512 + n];
            dst = n * 512 + k;
            dh = WUt_h;
        }
        dh[dst] = f2bf(val);
    }
}

// ---------------------------------------------------------------------------
// Fused QV projection: each block computes a 64-row tile for Q-head y AND
// V-head y from ONE staged A tile (X re-read 16 -> 8 passes). grid (128, 8)
// = 1024 blocks. Per-output math identical to the previous gemm_qv.
// ---------------------------------------------------------------------------
__global__ __launch_bounds__(256) void gemm_qv2(
    const u16* __restrict__ Ah_g,
    const u16* __restrict__ BQ, const u16* __restrict__ BV,
    u16* __restrict__ Qh,           // Q (prescaled bf16)
    u16* __restrict__ Vh,           // V natural
    u16* __restrict__ Vt)           // V transposed
{
    __shared__ u16 Ah[64][64];
    __shared__ u16 Bq[64][64];
    __shared__ u16 Bv[64][64];

    const int tid = threadIdx.x;
    const int w = tid >> 6, lane = tid & 63;
    const int lg = lane >> 4, ln = lane & 15;
    const int r0 = blockIdx.x * 64;
    const int y = blockIdx.y;           // head

    const u16* Bq_g = BQ + (size_t)y * 32768;
    const u16* Bv_g = BV + (size_t)y * 32768;

    const int r_a = tid >> 3;
    const int kc  = tid & 7;
    const int wcol = (kc * 8) ^ ((r_a & 7) << 3);
    const size_t gA = (size_t)(r0 + r_a) * DM + kc * 8;
    const size_t gB = (size_t)r_a * 512 + kc * 8;

    bf16x8 a0h, a1h, q0h, q1h, v0h, v1h;

    #define GLOAD(k0)                                                   \
        a0h = *(const bf16x8*)(Ah_g + gA + (k0));                       \
        a1h = *(const bf16x8*)(Ah_g + gA + 32 * DM + (k0));             \
        q0h = *(const bf16x8*)(Bq_g + gB + (k0));                       \
        q1h = *(const bf16x8*)(Bq_g + gB + 32 * 512 + (k0));            \
        v0h = *(const bf16x8*)(Bv_g + gB + (k0));                       \
        v1h = *(const bf16x8*)(Bv_g + gB + 32 * 512 + (k0));

    f32x4 accq[4], accv[4];
    #pragma unroll
    for (int j = 0; j < 4; ++j) {
        accq[j] = (f32x4){0.f, 0.f, 0.f, 0.f};
        accv[j] = (f32x4){0.f, 0.f, 0.f, 0.f};
    }

    GLOAD(0);

    for (int kt = 0; kt < 8; ++kt) {
        __syncthreads();
        *(bf16x8*)&Ah[r_a][wcol]      = a0h;
        *(bf16x8*)&Ah[r_a + 32][wcol] = a1h;
        *(bf16x8*)&Bq[r_a][wcol]      = q0h;
        *(bf16x8*)&Bq[r_a + 32][wcol] = q1h;
        *(bf16x8*)&Bv[r_a][wcol]      = v0h;
        *(bf16x8*)&Bv[r_a + 32][wcol] = v1h;
        __syncthreads();
        if (kt < 7) { GLOAD((kt + 1) * 64); }

        #pragma unroll
        for (int kk = 0; kk < 2; ++kk) {
            const int fc = (kk * 32 + lg * 8) ^ ((ln & 7) << 3);
            bf16x8 ah = *(const bf16x8*)&Ah[w * 16 + ln][fc];
            bf16x8 bq2[4], bv2[4];
            #pragma unroll
            for (int nj = 0; nj < 4; ++nj) {
                bq2[nj] = *(const bf16x8*)&Bq[nj * 16 + ln][fc];
                bv2[nj] = *(const bf16x8*)&Bv[nj * 16 + ln][fc];
            }
            #pragma unroll
            for (int nj = 0; nj < 4; ++nj) {
                accq[nj] = MFMA(ah, bq2[nj], accq[nj]);
                accv[nj] = MFMA(ah, bv2[nj], accv[nj]);
            }
        }
    }
    #undef GLOAD

    const float qscale = 0.18033688f;   // log2(e)/8
    const int tb = r0 + w * 16 + lg * 4;
    const int bh = (tb >> 12) * NH + y;
    const size_t obase = (size_t)bh * TSEQ * HS;
    #pragma unroll
    for (int nj = 0; nj < 4; ++nj) {
        int n = nj * 16 + ln;
        u16 hb[4];
        // Q output
        #pragma unroll
        for (int r = 0; r < 4; ++r) {
            int t = tb + r;
            Qh[obase + (size_t)(t & (TSEQ - 1)) * HS + n] =
                f2bf(accq[nj][r] * qscale);
        }
        // V output (natural + transposed packed)
        #pragma unroll
        for (int r = 0; r < 4; ++r) {
            hb[r] = f2bf(accv[nj][r]);
            int t = tb + r;
            Vh[obase + (size_t)(t & (TSEQ - 1)) * HS + n] = hb[r];
        }
        size_t toff = obase + (size_t)n * TSEQ + (tb & (TSEQ - 1));
        ull pk = (ull)hb[0] | ((ull)hb[1] << 16)
               | ((ull)hb[2] << 32) | ((ull)hb[3] << 48);
        *(ull*)(Vt + toff) = pk;
    }
}

// ---------------------------------------------------------------------------
// Output projection GEMM (1-term, 64x64 tile, grid 1024).
// ---------------------------------------------------------------------------
__global__ __launch_bounds__(256) void gemm_out(
    const u16* __restrict__ Ah_g, const u16* __restrict__ Bt_h,
    float* __restrict__ Of)
{
    __shared__ u16 Ah[64][64];
    __shared__ u16 Bh[64][64];

    const int tid = threadIdx.x;
    const int w = tid >> 6, lane = tid & 63;
    const int lg = lane >> 4, ln = lane & 15;
    const int r0 = blockIdx.x * 64;
    const int y = blockIdx.y;

    const u16* Bsh = Bt_h + (size_t)y * 64 * 512;

    const int r_a = tid >> 3;
    const int kc  = tid & 7;
    const int wcol = (kc * 8) ^ ((r_a & 7) << 3);
    const size_t gA = (size_t)(r0 + r_a) * DM + kc * 8;
    const size_t gB = (size_t)r_a * 512 + kc * 8;

    bf16x8 a0h, a1h, b0h, b1h;

    #define GLOAD(k0)                                                   \
        a0h = *(const bf16x8*)(Ah_g + gA + (k0));                       \
        a1h = *(const bf16x8*)(Ah_g + gA + 32 * DM + (k0));             \
        b0h = *(const bf16x8*)(Bsh + gB + (k0));                        \
        b1h = *(const bf16x8*)(Bsh + gB + 32 * 512 + (k0));

    f32x4 acc[4];
    #pragma unroll
    for (int j = 0; j < 4; ++j)
        acc[j] = (f32x4){0.f, 0.f, 0.f, 0.f};

    GLOAD(0);

    for (int kt = 0; kt < 8; ++kt) {
        __syncthreads();
        *(bf16x8*)&Ah[r_a][wcol]      = a0h;
        *(bf16x8*)&Ah[r_a + 32][wcol] = a1h;
        *(bf16x8*)&Bh[r_a][wcol]      = b0h;
        *(bf16x8*)&Bh[r_a + 32][wcol] = b1h;
        __syncthreads();
        if (kt < 7) { GLOAD((kt + 1) * 64); }

        #pragma unroll
        for (int kk = 0; kk < 2; ++kk) {
            const int fc = (kk * 32 + lg * 8) ^ ((ln & 7) << 3);
            bf16x8 ah = *(const bf16x8*)&Ah[w * 16 + ln][fc];
            bf16x8 bh2[4];
            #pragma unroll
            for (int nj = 0; nj < 4; ++nj)
                bh2[nj] = *(const bf16x8*)&Bh[nj * 16 + ln][fc];
            #pragma unroll
            for (int nj = 0; nj < 4; ++nj)
                acc[nj] = MFMA(ah, bh2[nj], acc[nj]);
        }
    }
    #undef GLOAD

    #pragma unroll
    for (int nj = 0; nj < 4; ++nj)
        #pragma unroll
        for (int r = 0; r < 4; ++r) {
            int t = r0 + w * 16 + lg * 4 + r;
            Of[(size_t)t * DM + y * 64 + nj * 16 + ln] = acc[nj][r];
        }
}

// ---------------------------------------------------------------------------
// Banded flash attention v11 (R21, proven): double-buffered V tiles, one
// barrier per 64-u chunk, Q bf16, lsum via ones-frag MFMA, defer-max,
// exp2 softmax, XCD swizzle, C hi-plane.
// ---------------------------------------------------------------------------
__global__ __launch_bounds__(256) void attn_v11(
    const u16* __restrict__ Qh_g,
    const u16* __restrict__ Vnh_g, const u16* __restrict__ Vth_g,
    u16* __restrict__ Ch)
{
    __shared__ u16 Vn_h[2][64][64];              // [buf][u][s^((u&7)<<3)]
    __shared__ u16 Vt_h[2][64][64];              // [buf][s][u^((s&7)<<3)]
    __shared__ unsigned Ps[4][16][32];           // per-wave [t][(u&31)^((t&7)<<2)]

    const int tid = threadIdx.x;
    const int w = tid >> 6, lane = tid & 63;
    const int lg = lane >> 4, ln = lane & 15;
    const int raw = blockIdx.x;
    const int swz = (raw & 7) * 128 + (raw >> 3);   // XCD-contiguous
    const int ttile = swz & 63;
    const int bh = swz >> 6;
    const int t0 = ttile * 64;
    const size_t base = (size_t)bh * TSEQ * HS;
    const u16* Qph = Qh_g + base;
    const u16* Vph = Vnh_g + base;
    const u16* Vth = Vth_g + base;   // [s][u], row stride TSEQ

    bf16x8 qh[2];
    #pragma unroll
    for (int kk = 0; kk < 2; ++kk) {
        size_t off = (size_t)(t0 + w * 16 + ln) * HS + kk * 32 + lg * 8;
        qh[kk] = *(const bf16x8*)(Qph + off);
    }

    bf16x8 ones_frag;
    #pragma unroll
    for (int e = 0; e < 8; ++e)
        ones_frag[e] = (ln == 0) ? (short)0x3F80 : (short)0;

    f32x4 o[4], o4;
    float m[4];
    #pragma unroll
    for (int j = 0; j < 4; ++j) {
        o[j] = (f32x4){0.f, 0.f, 0.f, 0.f};
        m[j] = -1e30f;
    }
    o4 = (f32x4){0.f, 0.f, 0.f, 0.f};

    int u_lo = t0 - CTX; if (u_lo < 0) u_lo = 0;
    int u_hi = t0 + 64 + CTX; if (u_hi > TSEQ) u_hi = TSEQ;

    const int sr = tid >> 3;            // 0..31
    const int c8 = (tid & 7) * 8;
    const int wcA = c8 ^ ((sr & 7) << 3);

    bf16x8 vn0h, vn1h, vt0h, vt1h;
    #define VL(u0v)                                                             \
        vn0h = *(const bf16x8*)(Vph + (size_t)((u0v) + sr) * HS + c8);          \
        vn1h = *(const bf16x8*)(Vph + (size_t)((u0v) + sr + 32) * HS + c8);     \
        vt0h = *(const bf16x8*)(Vth + (size_t)sr * TSEQ + (u0v) + c8);          \
        vt1h = *(const bf16x8*)(Vth + (size_t)(sr + 32) * TSEQ + (u0v) + c8);
    #define VSTORE(bufi)                                                        \
        *(bf16x8*)&Vn_h[bufi][sr][wcA]      = vn0h;                             \
        *(bf16x8*)&Vn_h[bufi][sr + 32][wcA] = vn1h;                             \
        *(bf16x8*)&Vt_h[bufi][sr][wcA]      = vt0h;                             \
        *(bf16x8*)&Vt_h[bufi][sr + 32][wcA] = vt1h;

    VL(u_lo);
    VSTORE(0);
    __syncthreads();

    int cur = 0;
    for (int u0 = u_lo; u0 < u_hi; u0 += 64) {
        const bool more = (u0 + 64 < u_hi);
        if (more) { VL(u0 + 64); }

        // ---- scores
        f32x4 s[4];
        #pragma unroll
        for (int j = 0; j < 4; ++j) s[j] = (f32x4){0.f, 0.f, 0.f, 0.f};

        #pragma unroll
        for (int kk = 0; kk < 2; ++kk) {
            const int fc = (kk * 32 + lg * 8) ^ ((ln & 7) << 3);
            bf16x8 vh[4];
            #pragma unroll
            for (int uj = 0; uj < 4; ++uj)
                vh[uj] = *(const bf16x8*)&Vn_h[cur][uj * 16 + ln][fc];
            #pragma unroll
            for (int uj = 0; uj < 4; ++uj)
                s[uj] = MFMA(qh[kk], vh[uj], s[uj]);
        }

        // ---- band mask
        bool needmask = ((t0 + 63 - u0) > CTX) || ((u0 + 63 - t0) > CTX);
        if (needmask) {
            #pragma unroll
            for (int uj = 0; uj < 4; ++uj)
                #pragma unroll
                for (int r = 0; r < 4; ++r) {
                    int t = t0 + w * 16 + lg * 4 + r;
                    int u = u0 + uj * 16 + ln;
                    int d = t - u; if (d < 0) d = -d;
                    if (d > CTX) s[uj][r] = -1e30f;
                }
        }

        // ---- online softmax (exp2 domain, DPP max, defer-max THR=8)
        float rm[4];
        bool need = false;
        #pragma unroll
        for (int r = 0; r < 4; ++r) {
            float v = fmaxf(fmaxf(s[0][r], s[1][r]), fmaxf(s[2][r], s[3][r]));
            rm[r] = row16_max(v);
            need |= (rm[r] > m[r] + 8.f);
        }
        if (__any(need)) {
            #pragma unroll
            for (int r = 0; r < 4; ++r) {
                float mn = fmaxf(m[r], rm[r]);
                float sc2 = exp2f(m[r] - mn);
                m[r] = mn;
                o4[r] *= sc2;
                #pragma unroll
                for (int sj = 0; sj < 4; ++sj)
                    o[sj][r] *= sc2;
            }
        }
        #pragma unroll
        for (int r = 0; r < 4; ++r)
            #pragma unroll
            for (int uj = 0; uj < 4; ++uj)
                s[uj][r] = exp2f(s[uj][r] - m[r]);

        // ---- PV; P bf16 (dup'd halves); lsum via ones-frag
        #pragma unroll
        for (int kk = 0; kk < 2; ++kk) {
            #pragma unroll
            for (int u2 = 0; u2 < 2; ++u2) {
                int uj = kk * 2 + u2;
                #pragma unroll
                for (int r = 0; r < 4; ++r) {
                    int trow = lg * 4 + r;
                    int ucol = (u2 * 16 + ln) ^ ((trow & 7) << 2);
                    Ps[w][trow][ucol] = bf16dup(s[uj][r]);
                }
            }

            bf16x8 ph, vth4[4];
            {
                int sw = (ln & 7) << 2;
                uint4 q0 = *(const uint4*)&Ps[w][ln][(lg * 8) ^ sw];
                uint4 q1 = *(const uint4*)&Ps[w][ln][(lg * 8 + 4) ^ sw];
                union { unsigned u[4]; bf16x8 v; } H;
                H.u[0] = __builtin_amdgcn_perm(q0.y, q0.x, 0x05040100u);
                H.u[1] = __builtin_amdgcn_perm(q0.w, q0.z, 0x05040100u);
                H.u[2] = __builtin_amdgcn_perm(q1.y, q1.x, 0x05040100u);
                H.u[3] = __builtin_amdgcn_perm(q1.w, q1.z, 0x05040100u);
                ph = H.v;
            }
            const int fct = (kk * 32 + lg * 8) ^ ((ln & 7) << 3);
            #pragma unroll
            for (int sj = 0; sj < 4; ++sj)
                vth4[sj] = *(const bf16x8*)&Vt_h[cur][sj * 16 + ln][fct];
            #pragma unroll
            for (int sj = 0; sj < 4; ++sj)
                o[sj] = MFMA(ph, vth4[sj], o[sj]);
            o4 = MFMA(ph, ones_frag, o4);
        }

        if (more) { VSTORE(cur ^ 1); }
        __syncthreads();
        cur ^= 1;
    }
    #undef VL
    #undef VSTORE

    // ---- epilogue
    const int b = bh >> 3, h = bh & 7;
    #pragma unroll
    for (int r = 0; r < 4; ++r) {
        float ls = __shfl(o4[r], (lane >> 4) << 4);
        float inv = 1.f / ls;
        int t = t0 + w * 16 + lg * 4 + r;
        #pragma unroll
        for (int sj = 0; sj < 4; ++sj) {
            int ss = sj * 16 + ln;
            float val = o[sj][r] * inv;
            size_t off = ((size_t)(b * TSEQ + t)) * DM + h * HS + ss;
            Ch[off] = f2bf(val);
        }
    }
}

// ---------------------------------------------------------------------------
extern "C" void kernel_launch(void* const* d_in, const int* in_sizes, int n_in,
                              void* d_out, int out_size, void* d_ws, size_t ws_size,
                              hipStream_t stream) {
    const float* X  = (const float*)d_in[0];
    const float* WQ = (const float*)d_in[1];
    const float* WV = (const float*)d_in[2];
    const float* WU = (const float*)d_in[3];
    float* out = (float*)d_out;

    const size_t SZ = 8388608;   // 8 MB region
    char* ws = (char*)d_ws;

    u16* Xh = (u16*)(ws);             // later reused as Ch
    u16* Qh = (u16*)(ws + 2 * SZ);
    u16* Vh = (u16*)(ws + 4 * SZ);
    u16* Vth = (u16*)(ws + 6 * SZ);
    char* wsw = ws + 8 * SZ;
    u16* WQt_h = (u16*)(wsw);
    u16* WVt_h = (u16*)(wsw + 524288);
    u16* WUt_h = (u16*)(wsw + 2 * 524288);

    presplit_xw<<<5120, 256, 0, stream>>>(X, WQ, WV, WU, Xh, WQt_h, WVt_h, WUt_h);
    gemm_qv2<<<dim3(128, 8), 256, 0, stream>>>(Xh, WQt_h, WVt_h, Qh, Vh, Vth);
    attn_v11<<<1024, 256, 0, stream>>>(Qh, Vh, Vth, Xh);
    gemm_out<<<dim3(128, 8), 256, 0, stream>>>(Xh, WUt_h, out);
}

// Round 23
// 71.482 us; speedup vs baseline: 1.0208x; 1.0208x over previous
//
#include <hip/hip_runtime.h>

#define TSEQ 4096
#define DM 512
#define NH 8
#define HS 64
#define CTX 256

typedef __attribute__((ext_vector_type(8))) short bf16x8;
typedef __attribute__((ext_vector_type(4))) float f32x4;
typedef unsigned short u16;
typedef unsigned long long ull;

__device__ __forceinline__ u16 f2bf(float x) {
    unsigned u = __float_as_uint(x);
    unsigned r = (u + 0x7fffu + ((u >> 16) & 1u)) >> 16;
    return (u16)r;
}
__device__ __forceinline__ float bf2f(u16 b) {
    return __uint_as_float(((unsigned)b) << 16);
}
__device__ __forceinline__ unsigned bf16dup(float p) {
    unsigned w;
    asm("v_cvt_pk_bf16_f32 %0, %1, %1" : "=v"(w) : "v"(p));
    return w;
}
template<int CTRL>
__device__ __forceinline__ float dpp_ror(float x) {
    int xi = __float_as_int(x);
    return __int_as_float(__builtin_amdgcn_update_dpp(xi, xi, CTRL, 0xf, 0xf, false));
}
__device__ __forceinline__ float row16_max(float v) {
    v = fmaxf(v, dpp_ror<0x121>(v));
    v = fmaxf(v, dpp_ror<0x122>(v));
    v = fmaxf(v, dpp_ror<0x124>(v));
    v = fmaxf(v, dpp_ror<0x128>(v));
    return v;
}

#define MFMA(a, b, c) __builtin_amdgcn_mfma_f32_16x16x32_bf16((a), (b), (c), 0, 0, 0)

// ---------------------------------------------------------------------------
// Fused pre-split: X (blocks 0..2047) + transposed weights (2048..5119).
// ---------------------------------------------------------------------------
__global__ __launch_bounds__(256) void presplit_xw(
    const float* __restrict__ X,
    const float* __restrict__ WQ, const float* __restrict__ WV,
    const float* __restrict__ WU,
    u16* __restrict__ Xh,
    u16* __restrict__ WQt_h, u16* __restrict__ WVt_h, u16* __restrict__ WUt_h)
{
    int b = blockIdx.x;
    if (b < 2048) {
        size_t idx = ((size_t)b * 256 + threadIdx.x) * 8;
        float4 p0 = *(const float4*)(X + idx);
        float4 p1 = *(const float4*)(X + idx + 4);
        float v[8] = {p0.x, p0.y, p0.z, p0.w, p1.x, p1.y, p1.z, p1.w};
        bf16x8 h;
        #pragma unroll
        for (int i = 0; i < 8; ++i) h[i] = (short)f2bf(v[i]);
        *(bf16x8*)(Xh + idx) = h;
    } else {
        int gidx = (b - 2048) * 256 + threadIdx.x;   // 0 .. 786431
        int a = gidx >> 18;                          // 0: WQ, 1: WV, 2: WU
        int r = gidx & 262143;
        float val;
        u16* dh;
        int dst;
        if (a < 2) {
            int h = r >> 15, s = (r >> 9) & 63, d = r & 511;
            const float* W = (a == 0) ? WQ : WV;
            val = W[h * 32768 + d * 64 + s];
            dst = h * 32768 + s * 512 + d;
            dh = (a == 0) ? WQt_h : WVt_h;
        } else {
            int n = r >> 9, k = r & 511;
            val = WU[k * 512 + n];
            dst = n * 512 + k;
            dh = WUt_h;
        }
        dh[dst] = f2bf(val);
    }
}

// ---------------------------------------------------------------------------
// QV projection GEMM (1-term, 128x64 tile). Q bf16 prescaled; V written in
// both layouts (natural + transposed via packed 8B fragment stores).
// ---------------------------------------------------------------------------
__global__ __launch_bounds__(256) void gemm_qv(
    const u16* __restrict__ Ah_g,
    const u16* __restrict__ B0h, const u16* __restrict__ B1h,
    u16* __restrict__ O0h,          // Qh
    u16* __restrict__ O1h,          // Vh (natural)
    u16* __restrict__ O1t)          // Vt (transposed)
{
    __shared__ u16 Ah[128][64];
    __shared__ u16 Bh[64][64];

    const int tid = threadIdx.x;
    const int w = tid >> 6, lane = tid & 63;
    const int lg = lane >> 4, ln = lane & 15;
    const int r0 = blockIdx.x * 128;
    const int y = blockIdx.y;

    const u16* Bsh = (y < 8) ? B0h + (size_t)y * 32768
                             : B1h + (size_t)(y - 8) * 32768;

    const int r_a = tid >> 3;
    const int kc  = tid & 7;
    const int wcol = (kc * 8) ^ ((r_a & 7) << 3);
    const size_t gA = (size_t)(r0 + r_a) * DM + kc * 8;
    const size_t gB = (size_t)r_a * 512 + kc * 8;

    bf16x8 a0h, a1h, a2h, a3h, b0h, b1h;

    #define GLOAD(k0)                                                   \
        a0h = *(const bf16x8*)(Ah_g + gA + (k0));                       \
        a1h = *(const bf16x8*)(Ah_g + gA + 32 * DM + (k0));             \
        a2h = *(const bf16x8*)(Ah_g + gA + 64 * DM + (k0));             \
        a3h = *(const bf16x8*)(Ah_g + gA + 96 * DM + (k0));             \
        b0h = *(const bf16x8*)(Bsh + gB + (k0));                        \
        b1h = *(const bf16x8*)(Bsh + gB + 32 * 512 + (k0));

    f32x4 acc[2][4];
    #pragma unroll
    for (int i = 0; i < 2; ++i)
        #pragma unroll
        for (int j = 0; j < 4; ++j)
            acc[i][j] = (f32x4){0.f, 0.f, 0.f, 0.f};

    GLOAD(0);

    for (int kt = 0; kt < 8; ++kt) {
        __syncthreads();
        *(bf16x8*)&Ah[r_a][wcol]      = a0h;
        *(bf16x8*)&Ah[r_a + 32][wcol] = a1h;
        *(bf16x8*)&Ah[r_a + 64][wcol] = a2h;
        *(bf16x8*)&Ah[r_a + 96][wcol] = a3h;
        *(bf16x8*)&Bh[r_a][wcol]      = b0h;
        *(bf16x8*)&Bh[r_a + 32][wcol] = b1h;
        __syncthreads();
        if (kt < 7) { GLOAD((kt + 1) * 64); }

        #pragma unroll
        for (int kk = 0; kk < 2; ++kk) {
            const int fc = (kk * 32 + lg * 8) ^ ((ln & 7) << 3);
            bf16x8 ah[2], bh2[4];
            #pragma unroll
            for (int ti = 0; ti < 2; ++ti)
                ah[ti] = *(const bf16x8*)&Ah[w * 32 + ti * 16 + ln][fc];
            #pragma unroll
            for (int nj = 0; nj < 4; ++nj)
                bh2[nj] = *(const bf16x8*)&Bh[nj * 16 + ln][fc];
            #pragma unroll
            for (int ti = 0; ti < 2; ++ti)
                #pragma unroll
                for (int nj = 0; nj < 4; ++nj)
                    acc[ti][nj] = MFMA(ah[ti], bh2[nj], acc[ti][nj]);
        }
    }
    #undef GLOAD

    const float qscale = (y < 8) ? 0.18033688f : 1.0f;   // log2(e)/8 for Q
    #pragma unroll
    for (int ti = 0; ti < 2; ++ti)
        #pragma unroll
        for (int nj = 0; nj < 4; ++nj) {
            u16 hb[4];
            #pragma unroll
            for (int r = 0; r < 4; ++r) {
                float val = acc[ti][nj][r] * qscale;
                hb[r] = f2bf(val);
                int t = r0 + w * 32 + ti * 16 + lg * 4 + r;
                int n = nj * 16 + ln;
                int bh = (t >> 12) * NH + (y & 7);
                size_t off = ((size_t)bh * TSEQ + (t & (TSEQ - 1))) * HS + n;
                if (y < 8) O0h[off] = hb[r];
                else       O1h[off] = hb[r];
            }
            if (y >= 8) {
                int t = r0 + w * 32 + ti * 16 + lg * 4;
                int n = nj * 16 + ln;
                int bh = (t >> 12) * NH + (y & 7);
                size_t off = (size_t)bh * TSEQ * HS + (size_t)n * TSEQ + (t & (TSEQ - 1));
                ull pk = (ull)hb[0] | ((ull)hb[1] << 16)
                       | ((ull)hb[2] << 32) | ((ull)hb[3] << 48);
                *(ull*)(O1t + off) = pk;
            }
        }
}

// ---------------------------------------------------------------------------
// Output projection GEMM (1-term, 64x64 tile, grid 1024).
// ---------------------------------------------------------------------------
__global__ __launch_bounds__(256) void gemm_out(
    const u16* __restrict__ Ah_g, const u16* __restrict__ Bt_h,
    float* __restrict__ Of)
{
    __shared__ u16 Ah[64][64];
    __shared__ u16 Bh[64][64];

    const int tid = threadIdx.x;
    const int w = tid >> 6, lane = tid & 63;
    const int lg = lane >> 4, ln = lane & 15;
    const int r0 = blockIdx.x * 64;
    const int y = blockIdx.y;

    const u16* Bsh = Bt_h + (size_t)y * 64 * 512;

    const int r_a = tid >> 3;
    const int kc  = tid & 7;
    const int wcol = (kc * 8) ^ ((r_a & 7) << 3);
    const size_t gA = (size_t)(r0 + r_a) * DM + kc * 8;
    const size_t gB = (size_t)r_a * 512 + kc * 8;

    bf16x8 a0h, a1h, b0h, b1h;

    #define GLOAD(k0)                                                   \
        a0h = *(const bf16x8*)(Ah_g + gA + (k0));                       \
        a1h = *(const bf16x8*)(Ah_g + gA + 32 * DM + (k0));             \
        b0h = *(const bf16x8*)(Bsh + gB + (k0));                        \
        b1h = *(const bf16x8*)(Bsh + gB + 32 * 512 + (k0));

    f32x4 acc[4];
    #pragma unroll
    for (int j = 0; j < 4; ++j)
        acc[j] = (f32x4){0.f, 0.f, 0.f, 0.f};

    GLOAD(0);

    for (int kt = 0; kt < 8; ++kt) {
        __syncthreads();
        *(bf16x8*)&Ah[r_a][wcol]      = a0h;
        *(bf16x8*)&Ah[r_a + 32][wcol] = a1h;
        *(bf16x8*)&Bh[r_a][wcol]      = b0h;
        *(bf16x8*)&Bh[r_a + 32][wcol] = b1h;
        __syncthreads();
        if (kt < 7) { GLOAD((kt + 1) * 64); }

        #pragma unroll
        for (int kk = 0; kk < 2; ++kk) {
            const int fc = (kk * 32 + lg * 8) ^ ((ln & 7) << 3);
            bf16x8 ah = *(const bf16x8*)&Ah[w * 16 + ln][fc];
            bf16x8 bh2[4];
            #pragma unroll
            for (int nj = 0; nj < 4; ++nj)
                bh2[nj] = *(const bf16x8*)&Bh[nj * 16 + ln][fc];
            #pragma unroll
            for (int nj = 0; nj < 4; ++nj)
                acc[nj] = MFMA(ah, bh2[nj], acc[nj]);
        }
    }
    #undef GLOAD

    #pragma unroll
    for (int nj = 0; nj < 4; ++nj)
        #pragma unroll
        for (int r = 0; r < 4; ++r) {
            int t = r0 + w * 16 + lg * 4 + r;
            Of[(size_t)t * DM + y * 64 + nj * 16 + ln] = acc[nj][r];
        }
}

// ---------------------------------------------------------------------------
// Banded flash attention v12 = R21's attn_v11 with VSTORE hoisted between
// softmax and PV: the next-chunk LDS writes drain under PV's MFMA+LDS work
// instead of stalling the barrier. Ordering proof: buf[cur^1]'s readers
// finished at the previous iteration's barrier, so the store may occur
// anywhere within this iteration. Numerics bit-identical.
// ---------------------------------------------------------------------------
__global__ __launch_bounds__(256) void attn_v12(
    const u16* __restrict__ Qh_g,
    const u16* __restrict__ Vnh_g, const u16* __restrict__ Vth_g,
    u16* __restrict__ Ch)
{
    __shared__ u16 Vn_h[2][64][64];              // [buf][u][s^((u&7)<<3)]
    __shared__ u16 Vt_h[2][64][64];              // [buf][s][u^((s&7)<<3)]
    __shared__ unsigned Ps[4][16][32];           // per-wave [t][(u&31)^((t&7)<<2)]

    const int tid = threadIdx.x;
    const int w = tid >> 6, lane = tid & 63;
    const int lg = lane >> 4, ln = lane & 15;
    const int raw = blockIdx.x;
    const int swz = (raw & 7) * 128 + (raw >> 3);   // XCD-contiguous
    const int ttile = swz & 63;
    const int bh = swz >> 6;
    const int t0 = ttile * 64;
    const size_t base = (size_t)bh * TSEQ * HS;
    const u16* Qph = Qh_g + base;
    const u16* Vph = Vnh_g + base;
    const u16* Vth = Vth_g + base;   // [s][u], row stride TSEQ

    bf16x8 qh[2];
    #pragma unroll
    for (int kk = 0; kk < 2; ++kk) {
        size_t off = (size_t)(t0 + w * 16 + ln) * HS + kk * 32 + lg * 8;
        qh[kk] = *(const bf16x8*)(Qph + off);
    }

    bf16x8 ones_frag;
    #pragma unroll
    for (int e = 0; e < 8; ++e)
        ones_frag[e] = (ln == 0) ? (short)0x3F80 : (short)0;

    f32x4 o[4], o4;
    float m[4];
    #pragma unroll
    for (int j = 0; j < 4; ++j) {
        o[j] = (f32x4){0.f, 0.f, 0.f, 0.f};
        m[j] = -1e30f;
    }
    o4 = (f32x4){0.f, 0.f, 0.f, 0.f};

    int u_lo = t0 - CTX; if (u_lo < 0) u_lo = 0;
    int u_hi = t0 + 64 + CTX; if (u_hi > TSEQ) u_hi = TSEQ;

    const int sr = tid >> 3;            // 0..31
    const int c8 = (tid & 7) * 8;
    const int wcA = c8 ^ ((sr & 7) << 3);

    bf16x8 vn0h, vn1h, vt0h, vt1h;
    #define VL(u0v)                                                             \
        vn0h = *(const bf16x8*)(Vph + (size_t)((u0v) + sr) * HS + c8);          \
        vn1h = *(const bf16x8*)(Vph + (size_t)((u0v) + sr + 32) * HS + c8);     \
        vt0h = *(const bf16x8*)(Vth + (size_t)sr * TSEQ + (u0v) + c8);          \
        vt1h = *(const bf16x8*)(Vth + (size_t)(sr + 32) * TSEQ + (u0v) + c8);
    #define VSTORE(bufi)                                                        \
        *(bf16x8*)&Vn_h[bufi][sr][wcA]      = vn0h;                             \
        *(bf16x8*)&Vn_h[bufi][sr + 32][wcA] = vn1h;                             \
        *(bf16x8*)&Vt_h[bufi][sr][wcA]      = vt0h;                             \
        *(bf16x8*)&Vt_h[bufi][sr + 32][wcA] = vt1h;

    VL(u_lo);
    VSTORE(0);
    __syncthreads();

    int cur = 0;
    for (int u0 = u_lo; u0 < u_hi; u0 += 64) {
        const bool more = (u0 + 64 < u_hi);
        if (more) { VL(u0 + 64); }

        // ---- scores
        f32x4 s[4];
        #pragma unroll
        for (int j = 0; j < 4; ++j) s[j] = (f32x4){0.f, 0.f, 0.f, 0.f};

        #pragma unroll
        for (int kk = 0; kk < 2; ++kk) {
            const int fc = (kk * 32 + lg * 8) ^ ((ln & 7) << 3);
            bf16x8 vh[4];
            #pragma unroll
            for (int uj = 0; uj < 4; ++uj)
                vh[uj] = *(const bf16x8*)&Vn_h[cur][uj * 16 + ln][fc];
            #pragma unroll
            for (int uj = 0; uj < 4; ++uj)
                s[uj] = MFMA(qh[kk], vh[uj], s[uj]);
        }

        // ---- band mask
        bool needmask = ((t0 + 63 - u0) > CTX) || ((u0 + 63 - t0) > CTX);
        if (needmask) {
            #pragma unroll
            for (int uj = 0; uj < 4; ++uj)
                #pragma unroll
                for (int r = 0; r < 4; ++r) {
                    int t = t0 + w * 16 + lg * 4 + r;
                    int u = u0 + uj * 16 + ln;
                    int d = t - u; if (d < 0) d = -d;
                    if (d > CTX) s[uj][r] = -1e30f;
                }
        }

        // ---- online softmax (exp2 domain, DPP max, defer-max THR=8)
        float rm[4];
        bool need = false;
        #pragma unroll
        for (int r = 0; r < 4; ++r) {
            float v = fmaxf(fmaxf(s[0][r], s[1][r]), fmaxf(s[2][r], s[3][r]));
            rm[r] = row16_max(v);
            need |= (rm[r] > m[r] + 8.f);
        }
        if (__any(need)) {
            #pragma unroll
            for (int r = 0; r < 4; ++r) {
                float mn = fmaxf(m[r], rm[r]);
                float sc2 = exp2f(m[r] - mn);
                m[r] = mn;
                o4[r] *= sc2;
                #pragma unroll
                for (int sj = 0; sj < 4; ++sj)
                    o[sj][r] *= sc2;
            }
        }
        #pragma unroll
        for (int r = 0; r < 4; ++r)
            #pragma unroll
            for (int uj = 0; uj < 4; ++uj)
                s[uj][r] = exp2f(s[uj][r] - m[r]);

        // ---- next-chunk LDS stores drain under PV (hoisted from loop tail)
        if (more) { VSTORE(cur ^ 1); }

        // ---- PV; P bf16 (dup'd halves); lsum via ones-frag
        #pragma unroll
        for (int kk = 0; kk < 2; ++kk) {
            #pragma unroll
            for (int u2 = 0; u2 < 2; ++u2) {
                int uj = kk * 2 + u2;
                #pragma unroll
                for (int r = 0; r < 4; ++r) {
                    int trow = lg * 4 + r;
                    int ucol = (u2 * 16 + ln) ^ ((trow & 7) << 2);
                    Ps[w][trow][ucol] = bf16dup(s[uj][r]);
                }
            }

            bf16x8 ph, vth4[4];
            {
                int sw = (ln & 7) << 2;
                uint4 q0 = *(const uint4*)&Ps[w][ln][(lg * 8) ^ sw];
                uint4 q1 = *(const uint4*)&Ps[w][ln][(lg * 8 + 4) ^ sw];
                union { unsigned u[4]; bf16x8 v; } H;
                H.u[0] = __builtin_amdgcn_perm(q0.y, q0.x, 0x05040100u);
                H.u[1] = __builtin_amdgcn_perm(q0.w, q0.z, 0x05040100u);
                H.u[2] = __builtin_amdgcn_perm(q1.y, q1.x, 0x05040100u);
                H.u[3] = __builtin_amdgcn_perm(q1.w, q1.z, 0x05040100u);
                ph = H.v;
            }
            const int fct = (kk * 32 + lg * 8) ^ ((ln & 7) << 3);
            #pragma unroll
            for (int sj = 0; sj < 4; ++sj)
                vth4[sj] = *(const bf16x8*)&Vt_h[cur][sj * 16 + ln][fct];
            #pragma unroll
            for (int sj = 0; sj < 4; ++sj)
                o[sj] = MFMA(ph, vth4[sj], o[sj]);
            o4 = MFMA(ph, ones_frag, o4);
        }

        __syncthreads();
        cur ^= 1;
    }
    #undef VL
    #undef VSTORE

    // ---- epilogue: lsum from ln==0 lanes, C hi-plane only
    const int b = bh >> 3, h = bh & 7;
    #pragma unroll
    for (int r = 0; r < 4; ++r) {
        float ls = __shfl(o4[r], (lane >> 4) << 4);
        float inv = 1.f / ls;
        int t = t0 + w * 16 + lg * 4 + r;
        #pragma unroll
        for (int sj = 0; sj < 4; ++sj) {
            int ss = sj * 16 + ln;
            float val = o[sj][r] * inv;
            size_t off = ((size_t)(b * TSEQ + t)) * DM + h * HS + ss;
            Ch[off] = f2bf(val);
        }
    }
}

// ---------------------------------------------------------------------------
extern "C" void kernel_launch(void* const* d_in, const int* in_sizes, int n_in,
                              void* d_out, int out_size, void* d_ws, size_t ws_size,
                              hipStream_t stream) {
    const float* X  = (const float*)d_in[0];
    const float* WQ = (const float*)d_in[1];
    const float* WV = (const float*)d_in[2];
    const float* WU = (const float*)d_in[3];
    float* out = (float*)d_out;

    const size_t SZ = 8388608;   // 8 MB region
    char* ws = (char*)d_ws;

    u16* Xh = (u16*)(ws);             // later reused as Ch
    u16* Qh = (u16*)(ws + 2 * SZ);
    u16* Vh = (u16*)(ws + 4 * SZ);
    u16* Vth = (u16*)(ws + 6 * SZ);
    char* wsw = ws + 8 * SZ;
    u16* WQt_h = (u16*)(wsw);
    u16* WVt_h = (u16*)(wsw + 524288);
    u16* WUt_h = (u16*)(wsw + 2 * 524288);

    presplit_xw<<<5120, 256, 0, stream>>>(X, WQ, WV, WU, Xh, WQt_h, WVt_h, WUt_h);
    gemm_qv<<<dim3(64, 16), 256, 0, stream>>>(Xh, WQt_h, WVt_h, Qh, Vh, Vth);
    attn_v12<<<1024, 256, 0, stream>>>(Qh, Vh, Vth, Xh);
    gemm_out<<<dim3(128, 8), 256, 0, stream>>>(Xh, WUt_h, out);
}

// Round 24
// 68.644 us; speedup vs baseline: 1.0630x; 1.0413x over previous
//
#include <hip/hip_runtime.h>

#define TSEQ 4096
#define DM 512
#define NH 8
#define HS 64
#define CTX 256

typedef __attribute__((ext_vector_type(8))) short bf16x8;
typedef __attribute__((ext_vector_type(4))) float f32x4;
typedef unsigned short u16;
typedef unsigned long long ull;

__device__ __forceinline__ u16 f2bf(float x) {
    unsigned u = __float_as_uint(x);
    unsigned r = (u + 0x7fffu + ((u >> 16) & 1u)) >> 16;
    return (u16)r;
}
__device__ __forceinline__ float bf2f(u16 b) {
    return __uint_as_float(((unsigned)b) << 16);
}
__device__ __forceinline__ unsigned bf16dup(float p) {
    unsigned w;
    asm("v_cvt_pk_bf16_f32 %0, %1, %1" : "=v"(w) : "v"(p));
    return w;
}
template<int CTRL>
__device__ __forceinline__ float dpp_ror(float x) {
    int xi = __float_as_int(x);
    return __int_as_float(__builtin_amdgcn_update_dpp(xi, xi, CTRL, 0xf, 0xf, false));
}
__device__ __forceinline__ float row16_max(float v) {
    v = fmaxf(v, dpp_ror<0x121>(v));
    v = fmaxf(v, dpp_ror<0x122>(v));
    v = fmaxf(v, dpp_ror<0x124>(v));
    v = fmaxf(v, dpp_ror<0x128>(v));
    return v;
}

#define MFMA(a, b, c) __builtin_amdgcn_mfma_f32_16x16x32_bf16((a), (b), (c), 0, 0, 0)

// ---------------------------------------------------------------------------
// Fused pre-split: X (blocks 0..2047) + transposed weights (2048..5119).
// ---------------------------------------------------------------------------
__global__ __launch_bounds__(256) void presplit_xw(
    const float* __restrict__ X,
    const float* __restrict__ WQ, const float* __restrict__ WV,
    const float* __restrict__ WU,
    u16* __restrict__ Xh,
    u16* __restrict__ WQt_h, u16* __restrict__ WVt_h, u16* __restrict__ WUt_h)
{
    int b = blockIdx.x;
    if (b < 2048) {
        size_t idx = ((size_t)b * 256 + threadIdx.x) * 8;
        float4 p0 = *(const float4*)(X + idx);
        float4 p1 = *(const float4*)(X + idx + 4);
        float v[8] = {p0.x, p0.y, p0.z, p0.w, p1.x, p1.y, p1.z, p1.w};
        bf16x8 h;
        #pragma unroll
        for (int i = 0; i < 8; ++i) h[i] = (short)f2bf(v[i]);
        *(bf16x8*)(Xh + idx) = h;
    } else {
        int gidx = (b - 2048) * 256 + threadIdx.x;   // 0 .. 786431
        int a = gidx >> 18;                          // 0: WQ, 1: WV, 2: WU
        int r = gidx & 262143;
        float val;
        u16* dh;
        int dst;
        if (a < 2) {
            int h = r >> 15, s = (r >> 9) & 63, d = r & 511;
            const float* W = (a == 0) ? WQ : WV;
            val = W[h * 32768 + d * 64 + s];
            dst = h * 32768 + s * 512 + d;
            dh = (a == 0) ? WQt_h : WVt_h;
        } else {
            int n = r >> 9, k = r & 511;
            val = WU[k * 512 + n];
            dst = n * 512 + k;
            dh = WUt_h;
        }
        dh[dst] = f2bf(val);
    }
}

// ---------------------------------------------------------------------------
// QV projection GEMM (1-term, 128x64 tile). Q bf16 prescaled; V written in
// both layouts (natural + transposed via packed 8B fragment stores).
// ---------------------------------------------------------------------------
__global__ __launch_bounds__(256) void gemm_qv(
    const u16* __restrict__ Ah_g,
    const u16* __restrict__ B0h, const u16* __restrict__ B1h,
    u16* __restrict__ O0h,          // Qh
    u16* __restrict__ O1h,          // Vh (natural)
    u16* __restrict__ O1t)          // Vt (transposed)
{
    __shared__ u16 Ah[128][64];
    __shared__ u16 Bh[64][64];

    const int tid = threadIdx.x;
    const int w = tid >> 6, lane = tid & 63;
    const int lg = lane >> 4, ln = lane & 15;
    const int r0 = blockIdx.x * 128;
    const int y = blockIdx.y;

    const u16* Bsh = (y < 8) ? B0h + (size_t)y * 32768
                             : B1h + (size_t)(y - 8) * 32768;

    const int r_a = tid >> 3;
    const int kc  = tid & 7;
    const int wcol = (kc * 8) ^ ((r_a & 7) << 3);
    const size_t gA = (size_t)(r0 + r_a) * DM + kc * 8;
    const size_t gB = (size_t)r_a * 512 + kc * 8;

    bf16x8 a0h, a1h, a2h, a3h, b0h, b1h;

    #define GLOAD(k0)                                                   \
        a0h = *(const bf16x8*)(Ah_g + gA + (k0));                       \
        a1h = *(const bf16x8*)(Ah_g + gA + 32 * DM + (k0));             \
        a2h = *(const bf16x8*)(Ah_g + gA + 64 * DM + (k0));             \
        a3h = *(const bf16x8*)(Ah_g + gA + 96 * DM + (k0));             \
        b0h = *(const bf16x8*)(Bsh + gB + (k0));                        \
        b1h = *(const bf16x8*)(Bsh + gB + 32 * 512 + (k0));

    f32x4 acc[2][4];
    #pragma unroll
    for (int i = 0; i < 2; ++i)
        #pragma unroll
        for (int j = 0; j < 4; ++j)
            acc[i][j] = (f32x4){0.f, 0.f, 0.f, 0.f};

    GLOAD(0);

    for (int kt = 0; kt < 8; ++kt) {
        __syncthreads();
        *(bf16x8*)&Ah[r_a][wcol]      = a0h;
        *(bf16x8*)&Ah[r_a + 32][wcol] = a1h;
        *(bf16x8*)&Ah[r_a + 64][wcol] = a2h;
        *(bf16x8*)&Ah[r_a + 96][wcol] = a3h;
        *(bf16x8*)&Bh[r_a][wcol]      = b0h;
        *(bf16x8*)&Bh[r_a + 32][wcol] = b1h;
        __syncthreads();
        if (kt < 7) { GLOAD((kt + 1) * 64); }

        #pragma unroll
        for (int kk = 0; kk < 2; ++kk) {
            const int fc = (kk * 32 + lg * 8) ^ ((ln & 7) << 3);
            bf16x8 ah[2], bh2[4];
            #pragma unroll
            for (int ti = 0; ti < 2; ++ti)
                ah[ti] = *(const bf16x8*)&Ah[w * 32 + ti * 16 + ln][fc];
            #pragma unroll
            for (int nj = 0; nj < 4; ++nj)
                bh2[nj] = *(const bf16x8*)&Bh[nj * 16 + ln][fc];
            #pragma unroll
            for (int ti = 0; ti < 2; ++ti)
                #pragma unroll
                for (int nj = 0; nj < 4; ++nj)
                    acc[ti][nj] = MFMA(ah[ti], bh2[nj], acc[ti][nj]);
        }
    }
    #undef GLOAD

    const float qscale = (y < 8) ? 0.18033688f : 1.0f;   // log2(e)/8 for Q
    #pragma unroll
    for (int ti = 0; ti < 2; ++ti)
        #pragma unroll
        for (int nj = 0; nj < 4; ++nj) {
            u16 hb[4];
            #pragma unroll
            for (int r = 0; r < 4; ++r) {
                float val = acc[ti][nj][r] * qscale;
                hb[r] = f2bf(val);
                int t = r0 + w * 32 + ti * 16 + lg * 4 + r;
                int n = nj * 16 + ln;
                int bh = (t >> 12) * NH + (y & 7);
                size_t off = ((size_t)bh * TSEQ + (t & (TSEQ - 1))) * HS + n;
                if (y < 8) O0h[off] = hb[r];
                else       O1h[off] = hb[r];
            }
            if (y >= 8) {
                int t = r0 + w * 32 + ti * 16 + lg * 4;
                int n = nj * 16 + ln;
                int bh = (t >> 12) * NH + (y & 7);
                size_t off = (size_t)bh * TSEQ * HS + (size_t)n * TSEQ + (t & (TSEQ - 1));
                ull pk = (ull)hb[0] | ((ull)hb[1] << 16)
                       | ((ull)hb[2] << 32) | ((ull)hb[3] << 48);
                *(ull*)(O1t + off) = pk;
            }
        }
}

// ---------------------------------------------------------------------------
// Output projection GEMM (1-term, 64x64 tile, grid 1024).
// ---------------------------------------------------------------------------
__global__ __launch_bounds__(256) void gemm_out(
    const u16* __restrict__ Ah_g, const u16* __restrict__ Bt_h,
    float* __restrict__ Of)
{
    __shared__ u16 Ah[64][64];
    __shared__ u16 Bh[64][64];

    const int tid = threadIdx.x;
    const int w = tid >> 6, lane = tid & 63;
    const int lg = lane >> 4, ln = lane & 15;
    const int r0 = blockIdx.x * 64;
    const int y = blockIdx.y;

    const u16* Bsh = Bt_h + (size_t)y * 64 * 512;

    const int r_a = tid >> 3;
    const int kc  = tid & 7;
    const int wcol = (kc * 8) ^ ((r_a & 7) << 3);
    const size_t gA = (size_t)(r0 + r_a) * DM + kc * 8;
    const size_t gB = (size_t)r_a * 512 + kc * 8;

    bf16x8 a0h, a1h, b0h, b1h;

    #define GLOAD(k0)                                                   \
        a0h = *(const bf16x8*)(Ah_g + gA + (k0));                       \
        a1h = *(const bf16x8*)(Ah_g + gA + 32 * DM + (k0));             \
        b0h = *(const bf16x8*)(Bsh + gB + (k0));                        \
        b1h = *(const bf16x8*)(Bsh + gB + 32 * 512 + (k0));

    f32x4 acc[4];
    #pragma unroll
    for (int j = 0; j < 4; ++j)
        acc[j] = (f32x4){0.f, 0.f, 0.f, 0.f};

    GLOAD(0);

    for (int kt = 0; kt < 8; ++kt) {
        __syncthreads();
        *(bf16x8*)&Ah[r_a][wcol]      = a0h;
        *(bf16x8*)&Ah[r_a + 32][wcol] = a1h;
        *(bf16x8*)&Bh[r_a][wcol]      = b0h;
        *(bf16x8*)&Bh[r_a + 32][wcol] = b1h;
        __syncthreads();
        if (kt < 7) { GLOAD((kt + 1) * 64); }

        #pragma unroll
        for (int kk = 0; kk < 2; ++kk) {
            const int fc = (kk * 32 + lg * 8) ^ ((ln & 7) << 3);
            bf16x8 ah = *(const bf16x8*)&Ah[w * 16 + ln][fc];
            bf16x8 bh2[4];
            #pragma unroll
            for (int nj = 0; nj < 4; ++nj)
                bh2[nj] = *(const bf16x8*)&Bh[nj * 16 + ln][fc];
            #pragma unroll
            for (int nj = 0; nj < 4; ++nj)
                acc[nj] = MFMA(ah, bh2[nj], acc[nj]);
        }
    }
    #undef GLOAD

    #pragma unroll
    for (int nj = 0; nj < 4; ++nj)
        #pragma unroll
        for (int r = 0; r < 4; ++r) {
            int t = r0 + w * 16 + lg * 4 + r;
            Of[(size_t)t * DM + y * 64 + nj * 16 + ln] = acc[nj][r];
        }
}

// ---------------------------------------------------------------------------
// Banded flash attention v13 = R23's attn_v12 scaled to 8 waves / 128 rows
// per block with a wave-level live-chunk guard. The live set per wave is
// exactly the chunk set that wave iterated in v12 (verified for all
// tw mod 64 cases), so per-row numerics are bit-identical; only staging
// traffic and barrier count change (~1.8x fewer per row). LDS 48 KB.
// ---------------------------------------------------------------------------
__global__ __launch_bounds__(512) void attn_v13(
    const u16* __restrict__ Qh_g,
    const u16* __restrict__ Vnh_g, const u16* __restrict__ Vth_g,
    u16* __restrict__ Ch)
{
    __shared__ u16 Vn_h[2][64][64];              // [buf][u][s^((u&7)<<3)]
    __shared__ u16 Vt_h[2][64][64];              // [buf][s][u^((s&7)<<3)]
    __shared__ unsigned Ps[8][16][32];           // per-wave [t][(u&31)^((t&7)<<2)]

    const int tid = threadIdx.x;
    const int w = tid >> 6, lane = tid & 63;     // w in [0,8)
    const int lg = lane >> 4, ln = lane & 15;
    const int raw = blockIdx.x;                  // 512 blocks
    const int swz = (raw & 7) * 64 + (raw >> 3); // XCD-contiguous (512%8==0)
    const int ttile = swz & 31;
    const int bh = swz >> 5;
    const int t0 = ttile * 128;
    const int tw = t0 + w * 16;                  // this wave's 16 rows
    const size_t base = (size_t)bh * TSEQ * HS;
    const u16* Qph = Qh_g + base;
    const u16* Vph = Vnh_g + base;
    const u16* Vth = Vth_g + base;   // [s][u], row stride TSEQ

    bf16x8 qh[2];
    #pragma unroll
    for (int kk = 0; kk < 2; ++kk) {
        size_t off = (size_t)(tw + ln) * HS + kk * 32 + lg * 8;
        qh[kk] = *(const bf16x8*)(Qph + off);
    }

    bf16x8 ones_frag;
    #pragma unroll
    for (int e = 0; e < 8; ++e)
        ones_frag[e] = (ln == 0) ? (short)0x3F80 : (short)0;

    f32x4 o[4], o4;
    float m[4];
    #pragma unroll
    for (int j = 0; j < 4; ++j) {
        o[j] = (f32x4){0.f, 0.f, 0.f, 0.f};
        m[j] = -1e30f;
    }
    o4 = (f32x4){0.f, 0.f, 0.f, 0.f};

    int u_lo = t0 - CTX; if (u_lo < 0) u_lo = 0;
    int u_hi = t0 + 128 + CTX; if (u_hi > TSEQ) u_hi = TSEQ;

    // staging geometry: 512 threads cover one 64x64 u16 plane per op
    const int sr = tid >> 3;            // 0..63
    const int c8 = (tid & 7) * 8;
    const int wcA = c8 ^ ((sr & 7) << 3);

    bf16x8 vnh, vth_r;
    #define VL(u0v)                                                             \
        vnh   = *(const bf16x8*)(Vph + (size_t)((u0v) + sr) * HS + c8);         \
        vth_r = *(const bf16x8*)(Vth + (size_t)sr * TSEQ + (u0v) + c8);
    #define VSTORE(bufi)                                                        \
        *(bf16x8*)&Vn_h[bufi][sr][wcA] = vnh;                                   \
        *(bf16x8*)&Vt_h[bufi][sr][wcA] = vth_r;

    VL(u_lo);
    VSTORE(0);
    __syncthreads();

    int cur = 0;
    for (int u0 = u_lo; u0 < u_hi; u0 += 64) {
        const bool more = (u0 + 64 < u_hi);
        if (more) { VL(u0 + 64); }

        // wave-level live guard: chunk intersects [tw-CTX, tw+15+CTX]
        const bool live = (u0 + 63 >= tw - CTX) && (u0 <= tw + 15 + CTX);

        f32x4 s[4];
        if (live) {
            // ---- scores
            #pragma unroll
            for (int j = 0; j < 4; ++j) s[j] = (f32x4){0.f, 0.f, 0.f, 0.f};

            #pragma unroll
            for (int kk = 0; kk < 2; ++kk) {
                const int fc = (kk * 32 + lg * 8) ^ ((ln & 7) << 3);
                bf16x8 vh[4];
                #pragma unroll
                for (int uj = 0; uj < 4; ++uj)
                    vh[uj] = *(const bf16x8*)&Vn_h[cur][uj * 16 + ln][fc];
                #pragma unroll
                for (int uj = 0; uj < 4; ++uj)
                    s[uj] = MFMA(qh[kk], vh[uj], s[uj]);
            }

            // ---- band mask
            bool needmask = ((tw + 15 - u0) > CTX) || ((u0 + 63 - tw) > CTX);
            if (needmask) {
                #pragma unroll
                for (int uj = 0; uj < 4; ++uj)
                    #pragma unroll
                    for (int r = 0; r < 4; ++r) {
                        int t = tw + lg * 4 + r;
                        int u = u0 + uj * 16 + ln;
                        int d = t - u; if (d < 0) d = -d;
                        if (d > CTX) s[uj][r] = -1e30f;
                    }
            }

            // ---- online softmax (exp2 domain, DPP max, defer-max THR=8)
            float rm[4];
            bool need = false;
            #pragma unroll
            for (int r = 0; r < 4; ++r) {
                float v = fmaxf(fmaxf(s[0][r], s[1][r]), fmaxf(s[2][r], s[3][r]));
                rm[r] = row16_max(v);
                need |= (rm[r] > m[r] + 8.f);
            }
            if (__any(need)) {
                #pragma unroll
                for (int r = 0; r < 4; ++r) {
                    float mn = fmaxf(m[r], rm[r]);
                    float sc2 = exp2f(m[r] - mn);
                    m[r] = mn;
                    o4[r] *= sc2;
                    #pragma unroll
                    for (int sj = 0; sj < 4; ++sj)
                        o[sj][r] *= sc2;
                }
            }
            #pragma unroll
            for (int r = 0; r < 4; ++r)
                #pragma unroll
                for (int uj = 0; uj < 4; ++uj)
                    s[uj][r] = exp2f(s[uj][r] - m[r]);
        }

        // ---- next-chunk LDS stores drain under PV (all threads)
        if (more) { VSTORE(cur ^ 1); }

        if (live) {
            // ---- PV; P bf16 (dup'd halves); lsum via ones-frag
            #pragma unroll
            for (int kk = 0; kk < 2; ++kk) {
                #pragma unroll
                for (int u2 = 0; u2 < 2; ++u2) {
                    int uj = kk * 2 + u2;
                    #pragma unroll
                    for (int r = 0; r < 4; ++r) {
                        int trow = lg * 4 + r;
                        int ucol = (u2 * 16 + ln) ^ ((trow & 7) << 2);
                        Ps[w][trow][ucol] = bf16dup(s[uj][r]);
                    }
                }

                bf16x8 ph, vth4[4];
                {
                    int sw = (ln & 7) << 2;
                    uint4 q0 = *(const uint4*)&Ps[w][ln][(lg * 8) ^ sw];
                    uint4 q1 = *(const uint4*)&Ps[w][ln][(lg * 8 + 4) ^ sw];
                    union { unsigned u[4]; bf16x8 v; } H;
                    H.u[0] = __builtin_amdgcn_perm(q0.y, q0.x, 0x05040100u);
                    H.u[1] = __builtin_amdgcn_perm(q0.w, q0.z, 0x05040100u);
                    H.u[2] = __builtin_amdgcn_perm(q1.y, q1.x, 0x05040100u);
                    H.u[3] = __builtin_amdgcn_perm(q1.w, q1.z, 0x05040100u);
                    ph = H.v;
                }
                const int fct = (kk * 32 + lg * 8) ^ ((ln & 7) << 3);
                #pragma unroll
                for (int sj = 0; sj < 4; ++sj)
                    vth4[sj] = *(const bf16x8*)&Vt_h[cur][sj * 16 + ln][fct];
                #pragma unroll
                for (int sj = 0; sj < 4; ++sj)
                    o[sj] = MFMA(ph, vth4[sj], o[sj]);
                o4 = MFMA(ph, ones_frag, o4);
            }
        }

        __syncthreads();
        cur ^= 1;
    }
    #undef VL
    #undef VSTORE

    // ---- epilogue: lsum from ln==0 lanes, C hi-plane only
    const int b = bh >> 3, h = bh & 7;
    #pragma unroll
    for (int r = 0; r < 4; ++r) {
        float ls = __shfl(o4[r], (lane >> 4) << 4);
        float inv = 1.f / ls;
        int t = tw + lg * 4 + r;
        #pragma unroll
        for (int sj = 0; sj < 4; ++sj) {
            int ss = sj * 16 + ln;
            float val = o[sj][r] * inv;
            size_t off = ((size_t)(b * TSEQ + t)) * DM + h * HS + ss;
            Ch[off] = f2bf(val);
        }
    }
}

// ---------------------------------------------------------------------------
extern "C" void kernel_launch(void* const* d_in, const int* in_sizes, int n_in,
                              void* d_out, int out_size, void* d_ws, size_t ws_size,
                              hipStream_t stream) {
    const float* X  = (const float*)d_in[0];
    const float* WQ = (const float*)d_in[1];
    const float* WV = (const float*)d_in[2];
    const float* WU = (const float*)d_in[3];
    float* out = (float*)d_out;

    const size_t SZ = 8388608;   // 8 MB region
    char* ws = (char*)d_ws;

    u16* Xh = (u16*)(ws);             // later reused as Ch
    u16* Qh = (u16*)(ws + 2 * SZ);
    u16* Vh = (u16*)(ws + 4 * SZ);
    u16* Vth = (u16*)(ws + 6 * SZ);
    char* wsw = ws + 8 * SZ;
    u16* WQt_h = (u16*)(wsw);
    u16* WVt_h = (u16*)(wsw + 524288);
    u16* WUt_h = (u16*)(wsw + 2 * 524288);

    presplit_xw<<<5120, 256, 0, stream>>>(X, WQ, WV, WU, Xh, WQt_h, WVt_h, WUt_h);
    gemm_qv<<<dim3(64, 16), 256, 0, stream>>>(Xh, WQt_h, WVt_h, Qh, Vh, Vth);
    attn_v13<<<512, 512, 0, stream>>>(Qh, Vh, Vth, Xh);
    gemm_out<<<dim3(128, 8), 256, 0, stream>>>(Xh, WUt_h, out);
}